// Round 6
// baseline (435.648 us; speedup 1.0000x reference)
//
#include <hip/hip_runtime.h>
#include <hip/hip_bf16.h>
#include <stdint.h>

// Problem constants (fixed by the reference)
#define M_ROWS 4096   // B
#define N_COLS 8192   // N
#define KDIM   512    // D

// GEMM: 256x256 tile, 8 waves (2M x 4N), BK=32 K-tiles, double-buffered LDS
#define BM 256
#define BN 256
#define BKT 32
#define NKT 16        // 512 / 32

typedef __attribute__((ext_vector_type(8))) __bf16 bf16x8;
typedef __attribute__((ext_vector_type(4))) float  f32x4;
typedef __attribute__((ext_vector_type(4))) int    i32x4;

// compiler-only fence + hw barrier (raw: no implicit vmcnt(0) drain)
#define BAR() do { asm volatile("" ::: "memory"); \
                   __builtin_amdgcn_s_barrier();  \
                   asm volatile("" ::: "memory"); } while (0)

// ---------- fp32 -> bf16 (RNE) ----------
__device__ __forceinline__ unsigned short f2bf(float f) {
  union { float f; uint32_t u; } v; v.f = f;
  uint32_t u = v.u;
  u += 0x7fffu + ((u >> 16) & 1u);
  return (unsigned short)(u >> 16);
}

// ---------- kernel 1: fp32 -> bf16 conversion only ----------
__global__ __launch_bounds__(256) void cvt_kernel(const float* __restrict__ A,
                                                  const float* __restrict__ S,
                                                  unsigned short* __restrict__ Abf,
                                                  unsigned short* __restrict__ Sbf) {
  int g = blockIdx.x * 256 + threadIdx.x;
  #pragma unroll
  for (int it = 0; it < 4; ++it) {
    int idx = g + it * 393216;
    float4 v; ushort4 o;
    if (idx < 524288) {
      v = reinterpret_cast<const float4*>(A)[idx];
      o.x = f2bf(v.x); o.y = f2bf(v.y); o.z = f2bf(v.z); o.w = f2bf(v.w);
      reinterpret_cast<ushort4*>(Abf)[idx] = o;
    } else {
      int q = idx - 524288;
      v = reinterpret_cast<const float4*>(S)[q];
      o.x = f2bf(v.x); o.y = f2bf(v.y); o.z = f2bf(v.z); o.w = f2bf(v.w);
      reinterpret_cast<ushort4*>(Sbf)[q] = o;
    }
  }
}

// ---------- GEMM helpers (verified R2 addressing, ring depth 2) ----------
__device__ __forceinline__ int swz_x(int r) { return (r & 3) ^ ((r >> 2) & 3); }

__device__ __forceinline__ bf16x8 lds_frag(const unsigned short* chunk, int r, int lk) {
  int g = lk ^ swz_x(r);
  return *reinterpret_cast<const bf16x8*>(chunk + r * 32 + g * 8);
}

__device__ __forceinline__ void stage_chunk(const unsigned short* __restrict__ srcBase,
                                            int tt, unsigned short* chunk,
                                            int w, int l) {
  #pragma unroll
  for (int jj = 0; jj < 2; ++jj) {
    int r = jj * 128 + w * 16 + (l >> 2);
    int g = (l & 3) ^ swz_x(r);
    const unsigned short* src = srcBase + (size_t)r * KDIM + tt * BKT + g * 8;
    __builtin_amdgcn_global_load_lds(
        (const __attribute__((address_space(1))) void*)src,
        (__attribute__((address_space(3))) void*)(chunk + jj * 4096 + w * 512),
        16, 0, 0);
  }
}

// consume scan pair of tile TSRC (register values -> conditional LDS write;
// value-wait is implicit vmcnt(6): scan(TSRC) is the OLDEST outstanding op,
// so nothing newer is forced to retire).
template<int TSRC>
__device__ __forceinline__ void consume_scan(i32x4 (&sv)[2][2], int* pos_lds, int tid) {
  #pragma unroll
  for (int j = 0; j < 2; ++j) {
    i32x4 v = sv[TSRC & 1][j];
    if (v[0] | v[1] | v[2] | v[3]) {
      int li4 = (TSRC * 512 + tid) * 2 + j;
      int sub = v[0] ? 0 : (v[1] ? 1 : (v[2] ? 2 : 3));
      pos_lds[li4 >> 11] = ((li4 & 2047) << 2) + sub;
    }
  }
}

// One K-tile, double-buffered. Per-tile issue order: stageA(T+1), stageB(T+1),
// scan(T+1). End of tile: consume scan(T) [implicit vmcnt(6)], then explicit
// vmcnt(2) retiring stage(T+1) only (scan(T+1) stays in flight). Staging never
// waits on an HBM-latency scan load (R4 failure mode eliminated).
template<int T>
__device__ __forceinline__ void do_tile(unsigned short (*lds)[2][BM * BKT],
                                        const unsigned short* __restrict__ Abase,
                                        const unsigned short* __restrict__ Sbase,
                                        const i32x4* __restrict__ scanB,
                                        int* pos_lds, i32x4 (&sv)[2][2],
                                        f32x4 (&acc)[8][4],
                                        int wr, int wc, int lr, int lk,
                                        int w, int lane, int tid) {
  const unsigned short* cA = lds[T & 1][0];
  const unsigned short* cB = lds[T & 1][1];

  bf16x8 bfr[4], afr[4];
  #pragma unroll
  for (int n = 0; n < 4; ++n) bfr[n] = lds_frag(cB, wc * 64 + n * 16 + lr, lk);
  #pragma unroll
  for (int m = 0; m < 4; ++m) afr[m] = lds_frag(cA, wr * 128 + m * 16 + lr, lk);
  if constexpr (T < NKT - 1) stage_chunk(Abase, T + 1, lds[(T + 1) & 1][0], w, lane);
  BAR();
  __builtin_amdgcn_s_setprio(1);
  #pragma unroll
  for (int m = 0; m < 4; ++m)
    #pragma unroll
    for (int n = 0; n < 4; ++n)
      acc[m][n] = __builtin_amdgcn_mfma_f32_16x16x32_bf16(afr[m], bfr[n],
                                                          acc[m][n], 0, 0, 0);
  __builtin_amdgcn_s_setprio(0);
  BAR();
  #pragma unroll
  for (int m = 0; m < 4; ++m) afr[m] = lds_frag(cA, wr * 128 + (m + 4) * 16 + lr, lk);
  if constexpr (T < NKT - 1) {
    stage_chunk(Sbase, T + 1, lds[(T + 1) & 1][1], w, lane);
    #pragma unroll
    for (int j = 0; j < 2; ++j)
      sv[(T + 1) & 1][j] =
          __builtin_nontemporal_load(scanB + (size_t)(((T + 1) * 512 + tid) * 2 + j));
  }
  BAR();
  __builtin_amdgcn_s_setprio(1);
  #pragma unroll
  for (int m = 0; m < 4; ++m)
    #pragma unroll
    for (int n = 0; n < 4; ++n)
      acc[m + 4][n] = __builtin_amdgcn_mfma_f32_16x16x32_bf16(afr[m], bfr[n],
                                                              acc[m + 4][n], 0, 0, 0);
  __builtin_amdgcn_s_setprio(0);
  consume_scan<T>(sv, pos_lds, tid);
  if constexpr (T < NKT - 1) asm volatile("s_waitcnt vmcnt(2)" ::: "memory");
  BAR();
}

// ---------- kernel 2: GEMM with overlapped one-hot scan (homogeneous) ----------
// 512 threads, 64 KB LDS -> 2 blocks/CU co-resident (whole 512-block grid
// resident): cross-block TLP hides any residual scan-latency exposure.
__global__ __launch_bounds__(512, 4) void gemm_scan_kernel(
    const unsigned short* __restrict__ Abf,
    const unsigned short* __restrict__ Sbf,
    const int* __restrict__ onehot,
    int* __restrict__ pos_idx,
    float* __restrict__ rsum, float* __restrict__ rmin) {
  __shared__ alignas(16) unsigned short lds[2][2][BM * BKT];  // 64 KB dbuf
  __shared__ int pos_lds[8];

  const int tid  = threadIdx.x;
  const int bx   = blockIdx.x;          // 512 blocks
  // XCD-aware swizzle (bijective, 512 % 8 == 0): XCD j gets a contiguous
  // wg-chunk -> 4 S-panels + all A-panels live in its L2/L3.
  const int wg   = ((bx & 7) << 6) | (bx >> 3);
  const int w    = tid >> 6;
  const int lane = tid & 63;
  const int wr   = w >> 2, wc = w & 3;
  const int lr   = lane & 15, lk = lane >> 4;
  const int rp   = wg & 15, cp = wg >> 4;
  const int rowBase = rp * BM;

  const unsigned short* Abase = Abf + (size_t)rowBase * KDIM;
  const unsigned short* Sbase = Sbf + (size_t)cp * BN * KDIM;
  const i32x4* scanB = reinterpret_cast<const i32x4*>(onehot + (size_t)bx * 8 * N_COLS);

  f32x4 acc[8][4];
  #pragma unroll
  for (int m = 0; m < 8; ++m)
    #pragma unroll
    for (int n = 0; n < 4; ++n)
      acc[m][n] = (f32x4){0.f, 0.f, 0.f, 0.f};
  i32x4 sv[2][2];

  // prologue: stage tile 0 (4 vm ops) + scan(0) (2 vm ops); vmcnt(2) retires
  // exactly the staging, leaving scan(0) in flight.
  stage_chunk(Abase, 0, lds[0][0], w, lane);
  stage_chunk(Sbase, 0, lds[0][1], w, lane);
  #pragma unroll
  for (int j = 0; j < 2; ++j)
    sv[0][j] = __builtin_nontemporal_load(scanB + (size_t)(tid * 2 + j));
  asm volatile("s_waitcnt vmcnt(2)" ::: "memory");
  BAR();

  do_tile<0>(lds, Abase, Sbase, scanB, pos_lds, sv, acc, wr, wc, lr, lk, w, lane, tid);
  do_tile<1>(lds, Abase, Sbase, scanB, pos_lds, sv, acc, wr, wc, lr, lk, w, lane, tid);
  do_tile<2>(lds, Abase, Sbase, scanB, pos_lds, sv, acc, wr, wc, lr, lk, w, lane, tid);
  do_tile<3>(lds, Abase, Sbase, scanB, pos_lds, sv, acc, wr, wc, lr, lk, w, lane, tid);
  do_tile<4>(lds, Abase, Sbase, scanB, pos_lds, sv, acc, wr, wc, lr, lk, w, lane, tid);
  do_tile<5>(lds, Abase, Sbase, scanB, pos_lds, sv, acc, wr, wc, lr, lk, w, lane, tid);
  do_tile<6>(lds, Abase, Sbase, scanB, pos_lds, sv, acc, wr, wc, lr, lk, w, lane, tid);
  do_tile<7>(lds, Abase, Sbase, scanB, pos_lds, sv, acc, wr, wc, lr, lk, w, lane, tid);
  do_tile<8>(lds, Abase, Sbase, scanB, pos_lds, sv, acc, wr, wc, lr, lk, w, lane, tid);
  do_tile<9>(lds, Abase, Sbase, scanB, pos_lds, sv, acc, wr, wc, lr, lk, w, lane, tid);
  do_tile<10>(lds, Abase, Sbase, scanB, pos_lds, sv, acc, wr, wc, lr, lk, w, lane, tid);
  do_tile<11>(lds, Abase, Sbase, scanB, pos_lds, sv, acc, wr, wc, lr, lk, w, lane, tid);
  do_tile<12>(lds, Abase, Sbase, scanB, pos_lds, sv, acc, wr, wc, lr, lk, w, lane, tid);
  do_tile<13>(lds, Abase, Sbase, scanB, pos_lds, sv, acc, wr, wc, lr, lk, w, lane, tid);
  do_tile<14>(lds, Abase, Sbase, scanB, pos_lds, sv, acc, wr, wc, lr, lk, w, lane, tid);
  do_tile<15>(lds, Abase, Sbase, scanB, pos_lds, sv, acc, wr, wc, lr, lk, w, lane, tid);
  __syncthreads();

  // ---- epilogue: per-row (sum, min) over this block's 256 cols ----
  // C/D layout: col = wc*64 + n*16 + (lane&15); row = wr*128 + m*16 + lk*4 + r.
  float* eps = (float*)&lds[0][0][0];     // [256 rows][4 cls][4 wc] = 16 KB
  float* epm = eps + 4096;                // + 16 KB (fits in 64 KB buffer)
  #pragma unroll
  for (int m = 0; m < 8; ++m)
    #pragma unroll
    for (int r = 0; r < 4; ++r) {
      float s_ = (acc[m][0][r] + acc[m][1][r]) + (acc[m][2][r] + acc[m][3][r]);
      float n_ = fminf(fminf(acc[m][0][r], acc[m][1][r]),
                       fminf(acc[m][2][r], acc[m][3][r]));
      s_ += __shfl_xor(s_, 4, 64);
      n_ = fminf(n_, __shfl_xor(n_, 4, 64));
      s_ += __shfl_xor(s_, 8, 64);
      n_ = fminf(n_, __shfl_xor(n_, 8, 64));
      if ((lane & 12) == 0) {
        int row = wr * 128 + m * 16 + lk * 4 + r;
        int cls = lane & 3;
        eps[(row * 4 + cls) * 4 + wc] = s_;
        epm[(row * 4 + cls) * 4 + wc] = n_;
      }
    }
  __syncthreads();
  #pragma unroll
  for (int item = tid; item < 1024; item += 512) {
    int row = item >> 2, cls = item & 3;
    float s0 = (eps[item * 4 + 0] + eps[item * 4 + 1]) +
               (eps[item * 4 + 2] + eps[item * 4 + 3]);
    float m0 = fminf(fminf(epm[item * 4 + 0], epm[item * 4 + 1]),
                     fminf(epm[item * 4 + 2], epm[item * 4 + 3]));
    size_t gi = (size_t)(rowBase + row) * 128 + cp * 4 + cls;
    rsum[gi] = s0;
    rmin[gi] = m0;
  }
  if (tid < 8) pos_idx[bx * 8 + tid] = pos_lds[tid];
}

// ---------- kernel 3: per-row loss via the no-clip identity ----------
// rowLoss = (R - p) - (N-1)(p-1) when min_n s >= p-1; guarded exact fp32
// slow path otherwise (never triggers for normalized random data).
__global__ __launch_bounds__(256) void fin1_kernel(
    const float* __restrict__ A, const float* __restrict__ Sm,
    const int* __restrict__ pos_idx,
    const float* __restrict__ rsum, const float* __restrict__ rmin,
    float* __restrict__ rowLoss) {
  const int w = threadIdx.x >> 6, lane = threadIdx.x & 63;
  #pragma unroll
  for (int i = 0; i < 2; ++i) {
    int row = blockIdx.x * 8 + w * 2 + i;
    int j = pos_idx[row];
    const float4* a4 = reinterpret_cast<const float4*>(A + (size_t)row * KDIM);
    const float4* s4 = reinterpret_cast<const float4*>(Sm + (size_t)j * KDIM);
    float4 x0 = a4[lane * 2], x1 = a4[lane * 2 + 1];
    float4 y0 = s4[lane * 2], y1 = s4[lane * 2 + 1];
    float dp = x0.x * y0.x + x0.y * y0.y + x0.z * y0.z + x0.w * y0.w
             + x1.x * y1.x + x1.y * y1.y + x1.z * y1.z + x1.w * y1.w;
    float rs = rsum[(size_t)row * 128 + lane] + rsum[(size_t)row * 128 + 64 + lane];
    float rm = fminf(rmin[(size_t)row * 128 + lane],
                     rmin[(size_t)row * 128 + 64 + lane]);
    #pragma unroll
    for (int off = 32; off > 0; off >>= 1) {
      dp += __shfl_down(dp, off, 64);
      rs += __shfl_down(rs, off, 64);
      rm = fminf(rm, __shfl_down(rm, off, 64));
    }
    float p  = __shfl(dp, 0, 64);
    float R  = __shfl(rs, 0, 64);
    float mn = __shfl(rm, 0, 64);
    float loss;
    if (mn >= p - 1.0f) {
      loss = (R - p) - (float)(N_COLS - 1) * (p - 1.0f);
    } else {
      float accv = 0.f;
      const float* arow = A + (size_t)row * KDIM;
      for (int n = lane; n < N_COLS; n += 64) {
        const float* srow = Sm + (size_t)n * KDIM;
        float d = 0.f;
        for (int k = 0; k < KDIM; ++k) d += arow[k] * srow[k];
        float h = fmaxf(d - p + 1.0f, 0.0f);
        accv += (n == j) ? 0.f : h;
      }
      #pragma unroll
      for (int off = 32; off > 0; off >>= 1) accv += __shfl_down(accv, off, 64);
      loss = __shfl(accv, 0, 64);
    }
    if (lane == 0) rowLoss[row] = loss;
  }
}

// ---------- kernel 4: deterministic final scalar ----------
__global__ __launch_bounds__(256) void fin2_kernel(const float* __restrict__ rowLoss,
                                                   float* __restrict__ out) {
  __shared__ double sd[256];
  double s = 0.0;
  for (int i = threadIdx.x; i < M_ROWS; i += 256) s += (double)rowLoss[i];
  sd[threadIdx.x] = s;
  __syncthreads();
  for (int st = 128; st > 0; st >>= 1) {
    if (threadIdx.x < st) sd[threadIdx.x] += sd[threadIdx.x + st];
    __syncthreads();
  }
  if (threadIdx.x == 0)
    *out = (float)(sd[0] / ((double)M_ROWS * (double)(N_COLS - 1)));
}

extern "C" void kernel_launch(void* const* d_in, const int* in_sizes, int n_in,
                              void* d_out, int out_size, void* d_ws, size_t ws_size,
                              hipStream_t stream) {
  const float* A  = (const float*)d_in[0];   // anchor [4096,512] f32
  const float* S  = (const float*)d_in[1];   // sample [8192,512] f32
  const int*   oh = (const int*)d_in[2];     // one-hot [4096,8192] int
  float* out = (float*)d_out;

  // workspace (~13.1 MB): pos | rsum | rmin | rowLoss | Abf | Sbf
  char* ws = (char*)d_ws;
  int*   pos_idx  = (int*)ws;                               // 16 KB
  float* rsum     = (float*)(ws + 16384);                   // 2 MB
  float* rmin     = (float*)(ws + 16384 + 2097152);         // 2 MB
  float* rowLoss  = (float*)(ws + 16384 + 4194304);         // 16 KB
  unsigned short* Abf = (unsigned short*)(ws + 16384 + 4194304 + 16384);  // 4 MB
  unsigned short* Sbf = Abf + (size_t)M_ROWS * KDIM;        // 8 MB

  cvt_kernel<<<1536, 256, 0, stream>>>(A, S, Abf, Sbf);
  gemm_scan_kernel<<<512, 512, 0, stream>>>(Abf, Sbf, oh, pos_idx, rsum, rmin);
  fin1_kernel<<<512, 256, 0, stream>>>(A, S, pos_idx, rsum, rmin, rowLoss);
  fin2_kernel<<<1, 256, 0, stream>>>(rowLoss, out);
}

// Round 7
// 86.764 us; speedup vs baseline: 5.0211x; 5.0211x over previous
//
#include <hip/hip_runtime.h>
#include <hip/hip_bf16.h>
#include <stdint.h>

// Problem constants (fixed by the reference)
#define M_ROWS 4096   // B
#define N_COLS 8192   // N
#define KDIM   512    // D

// GEMM: 256x256 tile, 8 waves (2M x 4N), BK=32 K-tiles, double-buffered LDS
#define BM 256
#define BN 256
#define BKT 32
#define NKT 16        // 512 / 32

typedef __attribute__((ext_vector_type(8))) __bf16 bf16x8;
typedef __attribute__((ext_vector_type(4))) float  f32x4;
typedef __attribute__((ext_vector_type(4))) int    i32x4;

// compiler-only fence + hw barrier (raw: no implicit vmcnt(0) drain)
#define BAR() do { asm volatile("" ::: "memory"); \
                   __builtin_amdgcn_s_barrier();  \
                   asm volatile("" ::: "memory"); } while (0)

// ---------- fp32 -> bf16 (RNE) ----------
__device__ __forceinline__ unsigned short f2bf(float f) {
  union { float f; uint32_t u; } v; v.f = f;
  uint32_t u = v.u;
  u += 0x7fffu + ((u >> 16) & 1u);
  return (unsigned short)(u >> 16);
}

// ---------- kernel 1: fp32 -> bf16 conversion only ----------
__global__ __launch_bounds__(256) void cvt_kernel(const float* __restrict__ A,
                                                  const float* __restrict__ S,
                                                  unsigned short* __restrict__ Abf,
                                                  unsigned short* __restrict__ Sbf) {
  int g = blockIdx.x * 256 + threadIdx.x;
  #pragma unroll
  for (int it = 0; it < 4; ++it) {
    int idx = g + it * 393216;
    float4 v; ushort4 o;
    if (idx < 524288) {
      v = reinterpret_cast<const float4*>(A)[idx];
      o.x = f2bf(v.x); o.y = f2bf(v.y); o.z = f2bf(v.z); o.w = f2bf(v.w);
      reinterpret_cast<ushort4*>(Abf)[idx] = o;
    } else {
      int q = idx - 524288;
      v = reinterpret_cast<const float4*>(S)[q];
      o.x = f2bf(v.x); o.y = f2bf(v.y); o.z = f2bf(v.z); o.w = f2bf(v.w);
      reinterpret_cast<ushort4*>(Sbf)[q] = o;
    }
  }
}

// ---------- GEMM helpers (verified R2 addressing, ring depth 2) ----------
__device__ __forceinline__ int swz_x(int r) { return (r & 3) ^ ((r >> 2) & 3); }

__device__ __forceinline__ bf16x8 lds_frag(const unsigned short* chunk, int r, int lk) {
  int g = lk ^ swz_x(r);
  return *reinterpret_cast<const bf16x8*>(chunk + r * 32 + g * 8);
}

__device__ __forceinline__ void stage_chunk(const unsigned short* __restrict__ srcBase,
                                            int tt, unsigned short* chunk,
                                            int w, int l) {
  #pragma unroll
  for (int jj = 0; jj < 2; ++jj) {
    int r = jj * 128 + w * 16 + (l >> 2);
    int g = (l & 3) ^ swz_x(r);
    const unsigned short* src = srcBase + (size_t)r * KDIM + tt * BKT + g * 8;
    __builtin_amdgcn_global_load_lds(
        (const __attribute__((address_space(1))) void*)src,
        (__attribute__((address_space(3))) void*)(chunk + jj * 4096 + w * 512),
        16, 0, 0);
  }
}

// consume scan pair of tile TSRC (register values -> conditional LDS write;
// value-wait is implicit vmcnt(6): scan(TSRC) is the OLDEST outstanding op,
// so nothing newer is forced to retire).
template<int TSRC>
__device__ __forceinline__ void consume_scan(i32x4 (&sv)[2][2], int* pos_lds, int tid) {
  #pragma unroll
  for (int j = 0; j < 2; ++j) {
    i32x4 v = sv[TSRC & 1][j];
    if (v[0] | v[1] | v[2] | v[3]) {
      int li4 = (TSRC * 512 + tid) * 2 + j;
      int sub = v[0] ? 0 : (v[1] ? 1 : (v[2] ? 2 : 3));
      pos_lds[li4 >> 11] = ((li4 & 2047) << 2) + sub;
    }
  }
}

// One K-tile, double-buffered. Per-tile issue order: stageA(T+1), stageB(T+1),
// scan(T+1). End of tile: consume scan(T) [implicit vmcnt(6)], then explicit
// vmcnt(2) retiring stage(T+1) only (scan(T+1) stays in flight). Staging never
// waits on an HBM-latency scan load (R4 failure mode eliminated).
template<int T>
__device__ __forceinline__ void do_tile(unsigned short (*lds)[2][BM * BKT],
                                        const unsigned short* __restrict__ Abase,
                                        const unsigned short* __restrict__ Sbase,
                                        const i32x4* __restrict__ scanB,
                                        int* pos_lds, i32x4 (&sv)[2][2],
                                        f32x4 (&acc)[8][4],
                                        int wr, int wc, int lr, int lk,
                                        int w, int lane, int tid) {
  const unsigned short* cA = lds[T & 1][0];
  const unsigned short* cB = lds[T & 1][1];

  bf16x8 bfr[4], afr[4];
  #pragma unroll
  for (int n = 0; n < 4; ++n) bfr[n] = lds_frag(cB, wc * 64 + n * 16 + lr, lk);
  #pragma unroll
  for (int m = 0; m < 4; ++m) afr[m] = lds_frag(cA, wr * 128 + m * 16 + lr, lk);
  if constexpr (T < NKT - 1) stage_chunk(Abase, T + 1, lds[(T + 1) & 1][0], w, lane);
  BAR();
  __builtin_amdgcn_s_setprio(1);
  #pragma unroll
  for (int m = 0; m < 4; ++m)
    #pragma unroll
    for (int n = 0; n < 4; ++n)
      acc[m][n] = __builtin_amdgcn_mfma_f32_16x16x32_bf16(afr[m], bfr[n],
                                                          acc[m][n], 0, 0, 0);
  __builtin_amdgcn_s_setprio(0);
  BAR();
  #pragma unroll
  for (int m = 0; m < 4; ++m) afr[m] = lds_frag(cA, wr * 128 + (m + 4) * 16 + lr, lk);
  if constexpr (T < NKT - 1) {
    stage_chunk(Sbase, T + 1, lds[(T + 1) & 1][1], w, lane);
    #pragma unroll
    for (int j = 0; j < 2; ++j)
      sv[(T + 1) & 1][j] =
          __builtin_nontemporal_load(scanB + (size_t)(((T + 1) * 512 + tid) * 2 + j));
  }
  BAR();
  __builtin_amdgcn_s_setprio(1);
  #pragma unroll
  for (int m = 0; m < 4; ++m)
    #pragma unroll
    for (int n = 0; n < 4; ++n)
      acc[m + 4][n] = __builtin_amdgcn_mfma_f32_16x16x32_bf16(afr[m], bfr[n],
                                                              acc[m + 4][n], 0, 0, 0);
  __builtin_amdgcn_s_setprio(0);
  consume_scan<T>(sv, pos_lds, tid);
  if constexpr (T < NKT - 1) asm volatile("s_waitcnt vmcnt(2)" ::: "memory");
  BAR();
}

// ---------- kernel 2: GEMM with overlapped one-hot scan (homogeneous) ----------
// 512 threads, 64 KB LDS, 128 VGPR -> 2 blocks/CU co-resident naturally
// (16 waves/CU at 128 VGPR): cross-block TLP hides residual scan latency.
// NOTE: __launch_bounds__ second arg MUST stay 2 — arg 4 made hipcc cap
// VGPRs at 64 and spill acc (R6: WRITE_SIZE 1.16 GB, 435 us).
__global__ __launch_bounds__(512, 2) void gemm_scan_kernel(
    const unsigned short* __restrict__ Abf,
    const unsigned short* __restrict__ Sbf,
    const int* __restrict__ onehot,
    int* __restrict__ pos_idx,
    float* __restrict__ rsum, float* __restrict__ rmin) {
  __shared__ alignas(16) unsigned short lds[2][2][BM * BKT];  // 64 KB dbuf
  __shared__ int pos_lds[8];

  const int tid  = threadIdx.x;
  const int bx   = blockIdx.x;          // 512 blocks
  // XCD-aware swizzle (bijective, 512 % 8 == 0): XCD j gets a contiguous
  // wg-chunk -> 4 S-panels + all A-panels live in its L2/L3.
  const int wg   = ((bx & 7) << 6) | (bx >> 3);
  const int w    = tid >> 6;
  const int lane = tid & 63;
  const int wr   = w >> 2, wc = w & 3;
  const int lr   = lane & 15, lk = lane >> 4;
  const int rp   = wg & 15, cp = wg >> 4;
  const int rowBase = rp * BM;

  const unsigned short* Abase = Abf + (size_t)rowBase * KDIM;
  const unsigned short* Sbase = Sbf + (size_t)cp * BN * KDIM;
  const i32x4* scanB = reinterpret_cast<const i32x4*>(onehot + (size_t)bx * 8 * N_COLS);

  f32x4 acc[8][4];
  #pragma unroll
  for (int m = 0; m < 8; ++m)
    #pragma unroll
    for (int n = 0; n < 4; ++n)
      acc[m][n] = (f32x4){0.f, 0.f, 0.f, 0.f};
  i32x4 sv[2][2];

  // prologue: stage tile 0 (4 vm ops) + scan(0) (2 vm ops); vmcnt(2) retires
  // exactly the staging, leaving scan(0) in flight.
  stage_chunk(Abase, 0, lds[0][0], w, lane);
  stage_chunk(Sbase, 0, lds[0][1], w, lane);
  #pragma unroll
  for (int j = 0; j < 2; ++j)
    sv[0][j] = __builtin_nontemporal_load(scanB + (size_t)(tid * 2 + j));
  asm volatile("s_waitcnt vmcnt(2)" ::: "memory");
  BAR();

  do_tile<0>(lds, Abase, Sbase, scanB, pos_lds, sv, acc, wr, wc, lr, lk, w, lane, tid);
  do_tile<1>(lds, Abase, Sbase, scanB, pos_lds, sv, acc, wr, wc, lr, lk, w, lane, tid);
  do_tile<2>(lds, Abase, Sbase, scanB, pos_lds, sv, acc, wr, wc, lr, lk, w, lane, tid);
  do_tile<3>(lds, Abase, Sbase, scanB, pos_lds, sv, acc, wr, wc, lr, lk, w, lane, tid);
  do_tile<4>(lds, Abase, Sbase, scanB, pos_lds, sv, acc, wr, wc, lr, lk, w, lane, tid);
  do_tile<5>(lds, Abase, Sbase, scanB, pos_lds, sv, acc, wr, wc, lr, lk, w, lane, tid);
  do_tile<6>(lds, Abase, Sbase, scanB, pos_lds, sv, acc, wr, wc, lr, lk, w, lane, tid);
  do_tile<7>(lds, Abase, Sbase, scanB, pos_lds, sv, acc, wr, wc, lr, lk, w, lane, tid);
  do_tile<8>(lds, Abase, Sbase, scanB, pos_lds, sv, acc, wr, wc, lr, lk, w, lane, tid);
  do_tile<9>(lds, Abase, Sbase, scanB, pos_lds, sv, acc, wr, wc, lr, lk, w, lane, tid);
  do_tile<10>(lds, Abase, Sbase, scanB, pos_lds, sv, acc, wr, wc, lr, lk, w, lane, tid);
  do_tile<11>(lds, Abase, Sbase, scanB, pos_lds, sv, acc, wr, wc, lr, lk, w, lane, tid);
  do_tile<12>(lds, Abase, Sbase, scanB, pos_lds, sv, acc, wr, wc, lr, lk, w, lane, tid);
  do_tile<13>(lds, Abase, Sbase, scanB, pos_lds, sv, acc, wr, wc, lr, lk, w, lane, tid);
  do_tile<14>(lds, Abase, Sbase, scanB, pos_lds, sv, acc, wr, wc, lr, lk, w, lane, tid);
  do_tile<15>(lds, Abase, Sbase, scanB, pos_lds, sv, acc, wr, wc, lr, lk, w, lane, tid);
  __syncthreads();

  // ---- epilogue: per-row (sum, min) over this block's 256 cols ----
  // C/D layout: col = wc*64 + n*16 + (lane&15); row = wr*128 + m*16 + lk*4 + r.
  float* eps = (float*)&lds[0][0][0];     // [256 rows][4 cls][4 wc] = 16 KB
  float* epm = eps + 4096;                // + 16 KB (fits in 64 KB buffer)
  #pragma unroll
  for (int m = 0; m < 8; ++m)
    #pragma unroll
    for (int r = 0; r < 4; ++r) {
      float s_ = (acc[m][0][r] + acc[m][1][r]) + (acc[m][2][r] + acc[m][3][r]);
      float n_ = fminf(fminf(acc[m][0][r], acc[m][1][r]),
                       fminf(acc[m][2][r], acc[m][3][r]));
      s_ += __shfl_xor(s_, 4, 64);
      n_ = fminf(n_, __shfl_xor(n_, 4, 64));
      s_ += __shfl_xor(s_, 8, 64);
      n_ = fminf(n_, __shfl_xor(n_, 8, 64));
      if ((lane & 12) == 0) {
        int row = wr * 128 + m * 16 + lk * 4 + r;
        int cls = lane & 3;
        eps[(row * 4 + cls) * 4 + wc] = s_;
        epm[(row * 4 + cls) * 4 + wc] = n_;
      }
    }
  __syncthreads();
  #pragma unroll
  for (int item = tid; item < 1024; item += 512) {
    int row = item >> 2, cls = item & 3;
    float s0 = (eps[item * 4 + 0] + eps[item * 4 + 1]) +
               (eps[item * 4 + 2] + eps[item * 4 + 3]);
    float m0 = fminf(fminf(epm[item * 4 + 0], epm[item * 4 + 1]),
                     fminf(epm[item * 4 + 2], epm[item * 4 + 3]));
    size_t gi = (size_t)(rowBase + row) * 128 + cp * 4 + cls;
    rsum[gi] = s0;
    rmin[gi] = m0;
  }
  if (tid < 8) pos_idx[bx * 8 + tid] = pos_lds[tid];
}

// ---------- kernel 3: per-row loss via the no-clip identity ----------
// rowLoss = (R - p) - (N-1)(p-1) when min_n s >= p-1; guarded exact fp32
// slow path otherwise (never triggers for normalized random data).
__global__ __launch_bounds__(256) void fin1_kernel(
    const float* __restrict__ A, const float* __restrict__ Sm,
    const int* __restrict__ pos_idx,
    const float* __restrict__ rsum, const float* __restrict__ rmin,
    float* __restrict__ rowLoss) {
  const int w = threadIdx.x >> 6, lane = threadIdx.x & 63;
  #pragma unroll
  for (int i = 0; i < 2; ++i) {
    int row = blockIdx.x * 8 + w * 2 + i;
    int j = pos_idx[row];
    const float4* a4 = reinterpret_cast<const float4*>(A + (size_t)row * KDIM);
    const float4* s4 = reinterpret_cast<const float4*>(Sm + (size_t)j * KDIM);
    float4 x0 = a4[lane * 2], x1 = a4[lane * 2 + 1];
    float4 y0 = s4[lane * 2], y1 = s4[lane * 2 + 1];
    float dp = x0.x * y0.x + x0.y * y0.y + x0.z * y0.z + x0.w * y0.w
             + x1.x * y1.x + x1.y * y1.y + x1.z * y1.z + x1.w * y1.w;
    float rs = rsum[(size_t)row * 128 + lane] + rsum[(size_t)row * 128 + 64 + lane];
    float rm = fminf(rmin[(size_t)row * 128 + lane],
                     rmin[(size_t)row * 128 + 64 + lane]);
    #pragma unroll
    for (int off = 32; off > 0; off >>= 1) {
      dp += __shfl_down(dp, off, 64);
      rs += __shfl_down(rs, off, 64);
      rm = fminf(rm, __shfl_down(rm, off, 64));
    }
    float p  = __shfl(dp, 0, 64);
    float R  = __shfl(rs, 0, 64);
    float mn = __shfl(rm, 0, 64);
    float loss;
    if (mn >= p - 1.0f) {
      loss = (R - p) - (float)(N_COLS - 1) * (p - 1.0f);
    } else {
      float accv = 0.f;
      const float* arow = A + (size_t)row * KDIM;
      for (int n = lane; n < N_COLS; n += 64) {
        const float* srow = Sm + (size_t)n * KDIM;
        float d = 0.f;
        for (int k = 0; k < KDIM; ++k) d += arow[k] * srow[k];
        float h = fmaxf(d - p + 1.0f, 0.0f);
        accv += (n == j) ? 0.f : h;
      }
      #pragma unroll
      for (int off = 32; off > 0; off >>= 1) accv += __shfl_down(accv, off, 64);
      loss = __shfl(accv, 0, 64);
    }
    if (lane == 0) rowLoss[row] = loss;
  }
}

// ---------- kernel 4: deterministic final scalar ----------
__global__ __launch_bounds__(256) void fin2_kernel(const float* __restrict__ rowLoss,
                                                   float* __restrict__ out) {
  __shared__ double sd[256];
  double s = 0.0;
  for (int i = threadIdx.x; i < M_ROWS; i += 256) s += (double)rowLoss[i];
  sd[threadIdx.x] = s;
  __syncthreads();
  for (int st = 128; st > 0; st >>= 1) {
    if (threadIdx.x < st) sd[threadIdx.x] += sd[threadIdx.x + st];
    __syncthreads();
  }
  if (threadIdx.x == 0)
    *out = (float)(sd[0] / ((double)M_ROWS * (double)(N_COLS - 1)));
}

extern "C" void kernel_launch(void* const* d_in, const int* in_sizes, int n_in,
                              void* d_out, int out_size, void* d_ws, size_t ws_size,
                              hipStream_t stream) {
  const float* A  = (const float*)d_in[0];   // anchor [4096,512] f32
  const float* S  = (const float*)d_in[1];   // sample [8192,512] f32
  const int*   oh = (const int*)d_in[2];     // one-hot [4096,8192] int
  float* out = (float*)d_out;

  // workspace (~13.1 MB): pos | rsum | rmin | rowLoss | Abf | Sbf
  char* ws = (char*)d_ws;
  int*   pos_idx  = (int*)ws;                               // 16 KB
  float* rsum     = (float*)(ws + 16384);                   // 2 MB
  float* rmin     = (float*)(ws + 16384 + 2097152);         // 2 MB
  float* rowLoss  = (float*)(ws + 16384 + 4194304);         // 16 KB
  unsigned short* Abf = (unsigned short*)(ws + 16384 + 4194304 + 16384);  // 4 MB
  unsigned short* Sbf = Abf + (size_t)M_ROWS * KDIM;        // 8 MB

  cvt_kernel<<<1536, 256, 0, stream>>>(A, S, Abf, Sbf);
  gemm_scan_kernel<<<512, 512, 0, stream>>>(Abf, Sbf, oh, pos_idx, rsum, rmin);
  fin1_kernel<<<512, 256, 0, stream>>>(A, S, pos_idx, rsum, rmin, rowLoss);
  fin2_kernel<<<1, 256, 0, stream>>>(rowLoss, out);
}

// Round 8
// 78.039 us; speedup vs baseline: 5.5824x; 1.1118x over previous
//
#include <hip/hip_runtime.h>
#include <stdint.h>

// Problem constants (fixed by the reference)
#define M_ROWS 4096   // B
#define N_COLS 8192   // N
#define KDIM   512    // D

// GEMM: 256x256 tile, 8 waves (2M x 4N), BK=32 K-tiles, 4-deep LDS ring, fp8
#define BM 256
#define BN 256
#define BKT 32
#define NKT 16        // 512 / 32

typedef __attribute__((ext_vector_type(4))) float  f32x4;
typedef __attribute__((ext_vector_type(4))) int    i32x4;

// compiler-only fence + hw barrier (raw: no implicit vmcnt(0) drain)
#define BAR() do { asm volatile("" ::: "memory"); \
                   __builtin_amdgcn_s_barrier();  \
                   asm volatile("" ::: "memory"); } while (0)

// ---------- fp32x4 -> packed OCP e4m3 (hardware cvt, saturating) ----------
__device__ __forceinline__ unsigned int cvt4_fp8(float4 v) {
  int r = 0;
  r = __builtin_amdgcn_cvt_pk_fp8_f32(v.x, v.y, r, false);  // bytes 0,1
  r = __builtin_amdgcn_cvt_pk_fp8_f32(v.z, v.w, r, true);   // bytes 2,3
  return (unsigned int)r;
}

// ---------- kernel 1: prep = fp32->fp8 cvt of A,S + one-hot scan ----------
// 4096 blocks x 256 thr; block b converts 384 float4 and scans one-hot row b.
__global__ __launch_bounds__(256) void prep_kernel(
    const float* __restrict__ A, const float* __restrict__ S,
    const int* __restrict__ onehot,
    unsigned char* __restrict__ A8, unsigned char* __restrict__ S8,
    int* __restrict__ pos_idx) {
  const int b = blockIdx.x, tid = threadIdx.x;

  // cvt slice (A: 524288 f4, S: 1048576 f4; 384 per block)
  #pragma unroll
  for (int i = 0; i < 2; ++i) {
    int li = tid + i * 256;
    if (li < 384) {
      int idx = b * 384 + li;
      if (idx < 524288) {
        float4 v = reinterpret_cast<const float4*>(A)[idx];
        reinterpret_cast<unsigned int*>(A8)[idx] = cvt4_fp8(v);
      } else {
        int q = idx - 524288;
        float4 v = reinterpret_cast<const float4*>(S)[q];
        reinterpret_cast<unsigned int*>(S8)[q] = cvt4_fp8(v);
      }
    }
  }

  // one-hot scan of row b (exactly one nonzero)
  const i32x4* row = reinterpret_cast<const i32x4*>(onehot + (size_t)b * N_COLS);
  #pragma unroll
  for (int i = 0; i < 8; ++i) {
    i32x4 v = __builtin_nontemporal_load(&row[i * 256 + tid]);
    if (v[0] | v[1] | v[2] | v[3]) {
      int j = (i * 256 + tid) * 4 + (v[0] ? 0 : (v[1] ? 1 : (v[2] ? 2 : 3)));
      pos_idx[b] = j;   // single writer per row
    }
  }
}

// ---------- GEMM helpers (fp8; R2 ring-4 skeleton) ----------
// LDS chunk: [256 rows][32 B] fp8 = 8 KB. Swizzle: 16B half-row h_lds holds
// source half h_lds ^ x1(r), x1(r)=(r>>2)&1 -> frag b64 reads are 2-way bank
// (free, m136); gload_lds dest stays linear, source pre-swizzled (rule 21).
__device__ __forceinline__ int x1(int r) { return (r >> 2) & 1; }

__device__ __forceinline__ long lds_frag8(const unsigned char* chunk, int r, int q) {
  int byt = r * 32 + (((q >> 1) ^ x1(r)) * 16) + (q & 1) * 8;
  return *reinterpret_cast<const long*>(chunk + byt);
}

__device__ __forceinline__ void stage_chunk8(const unsigned char* __restrict__ srcBase,
                                             int tt, unsigned char* chunk, int tid) {
  int r = tid >> 1, h = tid & 1;
  const unsigned char* src = srcBase + (size_t)r * KDIM + tt * BKT + (h ^ x1(r)) * 16;
  __builtin_amdgcn_global_load_lds(
      (const __attribute__((address_space(1))) void*)src,
      (__attribute__((address_space(3))) void*)(chunk + tid * 16),
      16, 0, 0);
}

// One K-tile, 2 phases, ring-4. Per-wave vmcnt ledger (1 op per staged chunk,
// A in ph0 + B in ph1): end of tile T outstanding = {A,B}(T+2),{A,B}(T+3) -> 4;
// vmcnt(4) retires {A,B}(T+1). T=13: vmcnt(2). T=14: vmcnt(0).
template<int T>
__device__ __forceinline__ void do_tile(unsigned char (*lds)[2][BM * BKT],
                                        const unsigned char* __restrict__ Abase,
                                        const unsigned char* __restrict__ Sbase,
                                        f32x4 (&acc)[8][4],
                                        int wr, int wc, int lr, int lk, int tid) {
  constexpr bool STAGE = (T <= NKT - 4);
  const unsigned char* cA = lds[T & 3][0];
  const unsigned char* cB = lds[T & 3][1];

  long bfr[4], afr[4];
  #pragma unroll
  for (int n = 0; n < 4; ++n) bfr[n] = lds_frag8(cB, wc * 64 + n * 16 + lr, lk);
  #pragma unroll
  for (int m = 0; m < 4; ++m) afr[m] = lds_frag8(cA, wr * 128 + m * 16 + lr, lk);
  if constexpr (STAGE) stage_chunk8(Abase, T + 3, lds[(T + 3) & 3][0], tid);
  BAR();
  __builtin_amdgcn_s_setprio(1);
  #pragma unroll
  for (int m = 0; m < 4; ++m)
    #pragma unroll
    for (int n = 0; n < 4; ++n)
      acc[m][n] = __builtin_amdgcn_mfma_f32_16x16x32_fp8_fp8(afr[m], bfr[n],
                                                             acc[m][n], 0, 0, 0);
  __builtin_amdgcn_s_setprio(0);
  BAR();
  #pragma unroll
  for (int m = 0; m < 4; ++m) afr[m] = lds_frag8(cA, wr * 128 + (m + 4) * 16 + lr, lk);
  if constexpr (STAGE) stage_chunk8(Sbase, T + 3, lds[(T + 3) & 3][1], tid);
  BAR();
  __builtin_amdgcn_s_setprio(1);
  #pragma unroll
  for (int m = 0; m < 4; ++m)
    #pragma unroll
    for (int n = 0; n < 4; ++n)
      acc[m + 4][n] = __builtin_amdgcn_mfma_f32_16x16x32_fp8_fp8(afr[m], bfr[n],
                                                                 acc[m + 4][n], 0, 0, 0);
  __builtin_amdgcn_s_setprio(0);
  if constexpr (T <= 12)      asm volatile("s_waitcnt vmcnt(4)" ::: "memory");
  else if constexpr (T == 13) asm volatile("s_waitcnt vmcnt(2)" ::: "memory");
  else if constexpr (T == 14) asm volatile("s_waitcnt vmcnt(0)" ::: "memory");
  BAR();
}

// ---------- kernel 2: fp8 MFMA GEMM + per-row (sum,min) epilogue ----------
// 64 KB LDS + ~128 VGPR -> 2 blocks/CU co-resident: sibling block's waves
// hide this block's barrier/staging stalls (no scan coupling anywhere).
__global__ __launch_bounds__(512, 2) void gemm_kernel(
    const unsigned char* __restrict__ A8,
    const unsigned char* __restrict__ S8,
    float* __restrict__ rsum, float* __restrict__ rmin) {
  __shared__ alignas(16) unsigned char lds[4][2][BM * BKT];  // 64 KB ring
  const int tid  = threadIdx.x;
  const int bx   = blockIdx.x;          // 512 blocks
  // XCD-aware bijective swizzle (512 % 8 == 0)
  const int wg   = ((bx & 7) << 6) | (bx >> 3);
  const int w    = tid >> 6;
  const int lane = tid & 63;
  const int wr   = w >> 2, wc = w & 3;
  const int lr   = lane & 15, lk = lane >> 4;
  const int rp   = wg & 15, cp = wg >> 4;
  const int rowBase = rp * BM;

  const unsigned char* Abase = A8 + (size_t)rowBase * KDIM;
  const unsigned char* Sbase = S8 + (size_t)cp * BN * KDIM;

  f32x4 acc[8][4];
  #pragma unroll
  for (int m = 0; m < 8; ++m)
    #pragma unroll
    for (int n = 0; n < 4; ++n)
      acc[m][n] = (f32x4){0.f, 0.f, 0.f, 0.f};

  // prologue: stage tiles 0,1,2 (6 ops/wave); vmcnt(4) -> tile 0 landed
  #pragma unroll
  for (int tt = 0; tt < 3; ++tt) {
    stage_chunk8(Abase, tt, lds[tt][0], tid);
    stage_chunk8(Sbase, tt, lds[tt][1], tid);
  }
  asm volatile("s_waitcnt vmcnt(4)" ::: "memory");
  BAR();

  do_tile<0>(lds, Abase, Sbase, acc, wr, wc, lr, lk, tid);
  do_tile<1>(lds, Abase, Sbase, acc, wr, wc, lr, lk, tid);
  do_tile<2>(lds, Abase, Sbase, acc, wr, wc, lr, lk, tid);
  do_tile<3>(lds, Abase, Sbase, acc, wr, wc, lr, lk, tid);
  do_tile<4>(lds, Abase, Sbase, acc, wr, wc, lr, lk, tid);
  do_tile<5>(lds, Abase, Sbase, acc, wr, wc, lr, lk, tid);
  do_tile<6>(lds, Abase, Sbase, acc, wr, wc, lr, lk, tid);
  do_tile<7>(lds, Abase, Sbase, acc, wr, wc, lr, lk, tid);
  do_tile<8>(lds, Abase, Sbase, acc, wr, wc, lr, lk, tid);
  do_tile<9>(lds, Abase, Sbase, acc, wr, wc, lr, lk, tid);
  do_tile<10>(lds, Abase, Sbase, acc, wr, wc, lr, lk, tid);
  do_tile<11>(lds, Abase, Sbase, acc, wr, wc, lr, lk, tid);
  do_tile<12>(lds, Abase, Sbase, acc, wr, wc, lr, lk, tid);
  do_tile<13>(lds, Abase, Sbase, acc, wr, wc, lr, lk, tid);
  do_tile<14>(lds, Abase, Sbase, acc, wr, wc, lr, lk, tid);
  do_tile<15>(lds, Abase, Sbase, acc, wr, wc, lr, lk, tid);
  __syncthreads();

  // ---- epilogue: per-row (sum, min) over this block's 256 cols ----
  // C/D layout: col = wc*64 + n*16 + (lane&15); row = wr*128 + m*16 + lk*4 + r.
  float* eps = (float*)&lds[0][0][0];     // [256 rows][4 cls][4 wc] = 16 KB
  float* epm = eps + 4096;                // + 16 KB (fits in 64 KB)
  #pragma unroll
  for (int m = 0; m < 8; ++m)
    #pragma unroll
    for (int r = 0; r < 4; ++r) {
      float s_ = (acc[m][0][r] + acc[m][1][r]) + (acc[m][2][r] + acc[m][3][r]);
      float n_ = fminf(fminf(acc[m][0][r], acc[m][1][r]),
                       fminf(acc[m][2][r], acc[m][3][r]));
      s_ += __shfl_xor(s_, 4, 64);
      n_ = fminf(n_, __shfl_xor(n_, 4, 64));
      s_ += __shfl_xor(s_, 8, 64);
      n_ = fminf(n_, __shfl_xor(n_, 8, 64));
      if ((lane & 12) == 0) {
        int row = wr * 128 + m * 16 + lk * 4 + r;
        int cls = lane & 3;
        eps[(row * 4 + cls) * 4 + wc] = s_;
        epm[(row * 4 + cls) * 4 + wc] = n_;
      }
    }
  __syncthreads();
  #pragma unroll
  for (int item = tid; item < 1024; item += 512) {
    int row = item >> 2, cls = item & 3;
    float s0 = (eps[item * 4 + 0] + eps[item * 4 + 1]) +
               (eps[item * 4 + 2] + eps[item * 4 + 3]);
    float m0 = fminf(fminf(epm[item * 4 + 0], epm[item * 4 + 1]),
                     fminf(epm[item * 4 + 2], epm[item * 4 + 3]));
    size_t gi = (size_t)(rowBase + row) * 128 + cp * 4 + cls;
    rsum[gi] = s0;
    rmin[gi] = m0;
  }
}

// ---------- kernel 3: per-row loss via the no-clip identity ----------
// rowLoss = (R - p) - (N-1)(p-1) when min_n s >= p-1 (p in fp32); guarded
// exact fp32 slow path otherwise.
__global__ __launch_bounds__(256) void fin1_kernel(
    const float* __restrict__ A, const float* __restrict__ Sm,
    const int* __restrict__ pos_idx,
    const float* __restrict__ rsum, const float* __restrict__ rmin,
    float* __restrict__ rowLoss) {
  const int w = threadIdx.x >> 6, lane = threadIdx.x & 63;
  #pragma unroll
  for (int i = 0; i < 2; ++i) {
    int row = blockIdx.x * 8 + w * 2 + i;
    int j = pos_idx[row];
    const float4* a4 = reinterpret_cast<const float4*>(A + (size_t)row * KDIM);
    const float4* s4 = reinterpret_cast<const float4*>(Sm + (size_t)j * KDIM);
    float4 x0 = a4[lane * 2], x1_ = a4[lane * 2 + 1];
    float4 y0 = s4[lane * 2], y1_ = s4[lane * 2 + 1];
    float dp = x0.x * y0.x + x0.y * y0.y + x0.z * y0.z + x0.w * y0.w
             + x1_.x * y1_.x + x1_.y * y1_.y + x1_.z * y1_.z + x1_.w * y1_.w;
    float rs = rsum[(size_t)row * 128 + lane] + rsum[(size_t)row * 128 + 64 + lane];
    float rm = fminf(rmin[(size_t)row * 128 + lane],
                     rmin[(size_t)row * 128 + 64 + lane]);
    #pragma unroll
    for (int off = 32; off > 0; off >>= 1) {
      dp += __shfl_down(dp, off, 64);
      rs += __shfl_down(rs, off, 64);
      rm = fminf(rm, __shfl_down(rm, off, 64));
    }
    float p  = __shfl(dp, 0, 64);
    float R  = __shfl(rs, 0, 64);
    float mn = __shfl(rm, 0, 64);
    float loss;
    if (mn >= p - 1.0f) {
      loss = (R - p) - (float)(N_COLS - 1) * (p - 1.0f);
    } else {
      float accv = 0.f;
      const float* arow = A + (size_t)row * KDIM;
      for (int n = lane; n < N_COLS; n += 64) {
        const float* srow = Sm + (size_t)n * KDIM;
        float d = 0.f;
        for (int k = 0; k < KDIM; ++k) d += arow[k] * srow[k];
        float h = fmaxf(d - p + 1.0f, 0.0f);
        accv += (n == j) ? 0.f : h;
      }
      #pragma unroll
      for (int off = 32; off > 0; off >>= 1) accv += __shfl_down(accv, off, 64);
      loss = __shfl(accv, 0, 64);
    }
    if (lane == 0) rowLoss[row] = loss;
  }
}

// ---------- kernel 4: deterministic final scalar ----------
__global__ __launch_bounds__(256) void fin2_kernel(const float* __restrict__ rowLoss,
                                                   float* __restrict__ out) {
  __shared__ double sd[256];
  double s = 0.0;
  for (int i = threadIdx.x; i < M_ROWS; i += 256) s += (double)rowLoss[i];
  sd[threadIdx.x] = s;
  __syncthreads();
  for (int st = 128; st > 0; st >>= 1) {
    if (threadIdx.x < st) sd[threadIdx.x] += sd[threadIdx.x + st];
    __syncthreads();
  }
  if (threadIdx.x == 0)
    *out = (float)(sd[0] / ((double)M_ROWS * (double)(N_COLS - 1)));
}

extern "C" void kernel_launch(void* const* d_in, const int* in_sizes, int n_in,
                              void* d_out, int out_size, void* d_ws, size_t ws_size,
                              hipStream_t stream) {
  const float* A  = (const float*)d_in[0];   // anchor [4096,512] f32
  const float* S  = (const float*)d_in[1];   // sample [8192,512] f32
  const int*   oh = (const int*)d_in[2];     // one-hot [4096,8192] int
  float* out = (float*)d_out;

  // workspace (~10.3 MB): pos | rsum | rmin | rowLoss | A8 | S8
  char* ws = (char*)d_ws;
  int*   pos_idx  = (int*)ws;                               // 16 KB
  float* rsum     = (float*)(ws + 16384);                   // 2 MB
  float* rmin     = (float*)(ws + 16384 + 2097152);         // 2 MB
  float* rowLoss  = (float*)(ws + 16384 + 4194304);         // 16 KB
  unsigned char* A8 = (unsigned char*)(ws + 16384 + 4194304 + 16384);  // 2 MB
  unsigned char* S8 = A8 + (size_t)M_ROWS * KDIM;           // 4 MB

  prep_kernel<<<M_ROWS, 256, 0, stream>>>(A, S, oh, A8, S8, pos_idx);
  gemm_kernel<<<512, 512, 0, stream>>>(A8, S8, rsum, rmin);
  fin1_kernel<<<512, 256, 0, stream>>>(A, S, pos_idx, rsum, rmin, rowLoss);
  fin2_kernel<<<1, 256, 0, stream>>>(rowLoss, out);
}